// Round 1
// baseline (484.026 us; speedup 1.0000x reference)
//
#include <hip/hip_runtime.h>
#include <math.h>

// ---------------------------------------------------------------------------
// SpectralConv3d + Chebyshev-Fourier correction, fp32, pruned separable DFTs.
// B=4, C=O=32, H=W=D=64. Modes: kx in {0..11, 52..63} (24), ky same (24),
// kz in {0..11} (12).
// out = (1/64^3) * Re[ sum F[kx,ky,kz] * w^(kx h + ky w + kz d) * c_kz ]
//       + corr_scale * corr[b,o,d],  c_0 = 1, c_kz = 2 (kz>=1).
// ---------------------------------------------------------------------------

static __device__ __forceinline__ void fill_tw(float2* tw, int tid, int nthr) {
    // tw[m] = (cos(2 pi m / 64), sin(2 pi m / 64))
    for (int m = tid; m < 64; m += nthr) {
        float s, c;
        sincosf((float)m * 0.09817477042468103f, &s, &c);
        tw[m] = make_float2(c, s);
    }
}

// ---------------------------------------------------------------------------
// Kernel 1: fused forward DFT along D (64->12) and W (64->24).
// grid = B*C*H = 8192 blocks, 256 threads. X2[(bc*64+h)*288 + a*12 + kz]
// ---------------------------------------------------------------------------
__global__ __launch_bounds__(256) void k_fwd_zy(const float* __restrict__ x,
                                                float2* __restrict__ X2) {
    __shared__ float xt[64 * 68];        // [w][d], pad 68 to break conflicts
    __shared__ float2 z1[64 * 12];       // [w][kz]
    __shared__ float2 tw[64];
    const int tid = threadIdx.x;
    const int blk = blockIdx.x;          // (b*32+c)*64 + h
    fill_tw(tw, tid, 256);
    const float4* xrow4 = (const float4*)(x + (size_t)blk * 4096);
    for (int r = 0; r < 4; ++r) {
        int i4 = r * 256 + tid;          // 1024 float4 = 4096 floats
        int w = i4 >> 4, d4 = (i4 & 15) << 2;
        float4 v = xrow4[i4];
        *(float4*)&xt[w * 68 + d4] = v;
    }
    __syncthreads();
    // z-stage: thread = (w, q), q covers kz {3q..3q+2}. e^{-i 2pi kz d/64}
    {
        const int w = tid >> 2, kz0 = (tid & 3) * 3;
        float2 a0 = make_float2(0.f, 0.f), a1 = a0, a2 = a0;
        const float* xr = &xt[w * 68];
        for (int d = 0; d < 64; ++d) {
            float xv = xr[d];
            float2 t0 = tw[(kz0 * d) & 63];
            float2 t1 = tw[((kz0 + 1) * d) & 63];
            float2 t2 = tw[((kz0 + 2) * d) & 63];
            a0.x += xv * t0.x; a0.y -= xv * t0.y;
            a1.x += xv * t1.x; a1.y -= xv * t1.y;
            a2.x += xv * t2.x; a2.y -= xv * t2.y;
        }
        z1[w * 12 + kz0]     = a0;
        z1[w * 12 + kz0 + 1] = a1;
        z1[w * 12 + kz0 + 2] = a2;
    }
    __syncthreads();
    // y-stage: 288 outputs (a, kz), e^{-i 2pi ky w / 64}
    float2* xout = X2 + (size_t)blk * 288;
    for (int idx = tid; idx < 288; idx += 256) {
        int a = idx / 12, kz = idx - a * 12;
        int kyv = a < 12 ? a : a + 40;
        float2 acc = make_float2(0.f, 0.f);
        for (int w = 0; w < 64; ++w) {
            float2 z = z1[w * 12 + kz];
            float2 t = tw[(kyv * w) & 63];
            acc.x += z.x * t.x + z.y * t.y;   // z * (c - i s)
            acc.y += z.y * t.x - z.x * t.y;
        }
        xout[idx] = acc;
    }
}

// ---------------------------------------------------------------------------
// Kernel 2: forward DFT along H (64->24).
// grid = B*C*24 = 3072, 256 threads. X3[bc*6912 + ax*288 + ay*12 + kz]
// ---------------------------------------------------------------------------
__global__ __launch_bounds__(256) void k_fwd_x(const float2* __restrict__ X2,
                                               float2* __restrict__ X3) {
    __shared__ float2 s2[64 * 12];       // [h][kz]
    __shared__ float2 tw[64];
    const int tid = threadIdx.x;
    const int blk = blockIdx.x;
    const int ay = blk % 24, bc = blk / 24;
    fill_tw(tw, tid, 256);
    const float2* src = X2 + (size_t)bc * (64 * 288) + ay * 12;
    for (int i = tid; i < 768; i += 256) {
        int hh = i / 12, kz = i - hh * 12;
        s2[i] = src[hh * 288 + kz];
    }
    __syncthreads();
    float2* dst = X3 + (size_t)bc * 6912 + ay * 12;
    for (int idx = tid; idx < 288; idx += 256) {
        int ax = idx / 12, kz = idx - ax * 12;
        int kxv = ax < 12 ? ax : ax + 40;
        float2 acc = make_float2(0.f, 0.f);
        for (int hh = 0; hh < 64; ++hh) {
            float2 z = s2[hh * 12 + kz];
            float2 t = tw[(kxv * hh) & 63];
            acc.x += z.x * t.x + z.y * t.y;   // z * (c - i s)
            acc.y += z.y * t.x - z.x * t.y;
        }
        dst[ax * 288 + kz] = acc;
    }
}

// ---------------------------------------------------------------------------
// Kernel 3: mode mixing F[b,o,m] = sum_i X3[b,i,m] * (wre + i wim)[i,o,m].
// grid = 24*24 = 576 blocks (one (ax,ay)), 384 threads = (o,kz).
// Weights streamed from global exactly once in total.
// ---------------------------------------------------------------------------
__global__ __launch_bounds__(384) void k_mix(const float2* __restrict__ X3,
                                             float2* __restrict__ F,
        const float* __restrict__ w1re, const float* __restrict__ w1im,
        const float* __restrict__ w2re, const float* __restrict__ w2im,
        const float* __restrict__ w3re, const float* __restrict__ w3im,
        const float* __restrict__ w4re, const float* __restrict__ w4im) {
    __shared__ float2 xs[128 * 12];      // [b*32+i][kz]
    const int tid = threadIdx.x;
    const int blk = blockIdx.x;
    const int ax = blk / 24, ay = blk % 24;
    const int cx = ax >= 12 ? 1 : 0, cy = ay >= 12 ? 1 : 0;
    const int m1 = ax - cx * 12, m2 = ay - cy * 12;
    const int sel = cx + cy * 2;         // 0:w1 (lo,lo) 1:w2 (hi,lo) 2:w3 (lo,hi) 3:w4
    const float* wre = sel == 0 ? w1re : sel == 1 ? w2re : sel == 2 ? w3re : w4re;
    const float* wim = sel == 0 ? w1im : sel == 1 ? w2im : sel == 2 ? w3im : w4im;
    const size_t moff = (size_t)ax * 288 + (size_t)ay * 12;
    for (int i = tid; i < 1536; i += 384) {
        int bi = i / 12, kz = i - bi * 12;
        xs[i] = X3[(size_t)bi * 6912 + moff + kz];
    }
    __syncthreads();
    const int o = tid / 12, kz = tid - (tid / 12) * 12;
    const int wbase = o * 1728 + m1 * 144 + m2 * 12 + kz;
    float2 A0 = make_float2(0.f, 0.f), A1 = A0, A2 = A0, A3 = A0;
    for (int i = 0; i < 32; ++i) {
        float wr = wre[i * 55296 + wbase];
        float wi = wim[i * 55296 + wbase];
        float2 x0 = xs[i * 12 + kz];
        float2 x1 = xs[(32 + i) * 12 + kz];
        float2 x2 = xs[(64 + i) * 12 + kz];
        float2 x3 = xs[(96 + i) * 12 + kz];
        A0.x += x0.x * wr - x0.y * wi; A0.y += x0.x * wi + x0.y * wr;
        A1.x += x1.x * wr - x1.y * wi; A1.y += x1.x * wi + x1.y * wr;
        A2.x += x2.x * wr - x2.y * wi; A2.y += x2.x * wi + x2.y * wr;
        A3.x += x3.x * wr - x3.y * wi; A3.y += x3.x * wi + x3.y * wr;
    }
    F[(size_t)(0 * 32 + o) * 6912 + moff + kz] = A0;
    F[(size_t)(1 * 32 + o) * 6912 + moff + kz] = A1;
    F[(size_t)(2 * 32 + o) * 6912 + moff + kz] = A2;
    F[(size_t)(3 * 32 + o) * 6912 + moff + kz] = A3;
}

// ---------------------------------------------------------------------------
// Kernel 4: inverse DFT along H (24->64). e^{+i 2pi kx h / 64}
// grid = B*O*24 = 3072, 256 threads. Y1[(bo*64+h)*288 + ay*12 + kz]
// ---------------------------------------------------------------------------
__global__ __launch_bounds__(256) void k_inv_x(const float2* __restrict__ F,
                                               float2* __restrict__ Y1) {
    __shared__ float2 fs[24 * 12];
    __shared__ float2 tw[64];
    const int tid = threadIdx.x;
    const int blk = blockIdx.x;
    const int ay = blk % 24, bo = blk / 24;
    fill_tw(tw, tid, 256);
    const float2* src = F + (size_t)bo * 6912 + ay * 12;
    for (int i = tid; i < 288; i += 256) {
        int ax = i / 12, kz = i - ax * 12;
        fs[i] = src[ax * 288 + kz];
    }
    __syncthreads();
    float2* dst = Y1 + (size_t)bo * (64 * 288) + ay * 12;
    for (int idx = tid; idx < 768; idx += 256) {
        int hh = idx / 12, kz = idx - (idx / 12) * 12;
        float2 acc = make_float2(0.f, 0.f);
        for (int ax = 0; ax < 24; ++ax) {
            int kxv = ax < 12 ? ax : ax + 40;
            float2 f = fs[ax * 12 + kz];
            float2 t = tw[(kxv * hh) & 63];
            acc.x += f.x * t.x - f.y * t.y;   // f * (c + i s)
            acc.y += f.x * t.y + f.y * t.x;
        }
        dst[hh * 288 + kz] = acc;
    }
}

// ---------------------------------------------------------------------------
// Kernel 5: CFT branch — segment-0 Chebyshev (T0,T1,T2) + 3-freq rDFT over W.
// grid = B*C = 128 blocks, 256 threads = (q=w-group)*64 + d.
// cft[(b*64+d)*576 + c*18 + k*6 + f*2 + {re,im}]
// ---------------------------------------------------------------------------
__global__ __launch_bounds__(256) void k_cft(const float* __restrict__ x,
                                             float* __restrict__ cft) {
    __shared__ float2 tw[64];
    __shared__ float red[3 * 64 * 18];
    const int tid = threadIdx.x;
    const int blk = blockIdx.x;          // b*32 + c
    const int d = tid & 63, q = tid >> 6;
    fill_tw(tw, tid, 256);
    __syncthreads();
    float aR[3][3] = {{0.f}}, aI[3][3] = {{0.f}};
    const float* xb = x + (size_t)blk * 262144;
    for (int wi = 0; wi < 16; ++wi) {
        const int w = q * 16 + wi;
        float c0 = 0.f, c1 = 0.f, c2 = 0.f;
        #pragma unroll
        for (int s = 0; s < 8; ++s) {
            float xv = xb[(size_t)(s * 64 + w) * 64 + d];
            float t = (2.0f * (float)s - 7.0f) * (1.0f / 7.0f);
            c0 += xv;
            c1 += xv * t;
            c2 += xv * (2.0f * t * t - 1.0f);
        }
        c0 *= 0.125f; c1 *= 0.125f; c2 *= 0.125f;
        #pragma unroll
        for (int f = 0; f < 3; ++f) {
            float2 t = tw[(f * w) & 63];
            aR[0][f] += c0 * t.x; aI[0][f] -= c0 * t.y;
            aR[1][f] += c1 * t.x; aI[1][f] -= c1 * t.y;
            aR[2][f] += c2 * t.x; aI[2][f] -= c2 * t.y;
        }
    }
    if (q > 0) {
        float* dst = &red[((q - 1) * 64 + d) * 18];
        #pragma unroll
        for (int k = 0; k < 3; ++k)
            #pragma unroll
            for (int f = 0; f < 3; ++f) {
                dst[k * 6 + f * 2]     = aR[k][f];
                dst[k * 6 + f * 2 + 1] = aI[k][f];
            }
    }
    __syncthreads();
    if (q == 0) {
        #pragma unroll
        for (int qq = 0; qq < 3; ++qq) {
            const float* sr = &red[(qq * 64 + d) * 18];
            #pragma unroll
            for (int k = 0; k < 3; ++k)
                #pragma unroll
                for (int f = 0; f < 3; ++f) {
                    aR[k][f] += sr[k * 6 + f * 2];
                    aI[k][f] += sr[k * 6 + f * 2 + 1];
                }
        }
        const int b = blk >> 5, c = blk & 31;
        float* dst = cft + (size_t)(b * 64 + d) * 576 + c * 18;
        #pragma unroll
        for (int k = 0; k < 3; ++k)
            #pragma unroll
            for (int f = 0; f < 3; ++f) {
                dst[k * 6 + f * 2]     = aR[k][f];
                dst[k * 6 + f * 2 + 1] = aI[k][f];
            }
    }
}

// ---------------------------------------------------------------------------
// Kernel 6: MLP 576->128 (exact GeLU) ->32, pre-scaled by corr_scale.
// grid = B*D = 256 rows, 128 threads. corr[(b*32+o)*64 + d]
// ---------------------------------------------------------------------------
__global__ __launch_bounds__(128) void k_mlp(const float* __restrict__ cft,
                                             const float* __restrict__ w1,
                                             const float* __restrict__ b1,
                                             const float* __restrict__ w2,
                                             const float* __restrict__ b2,
                                             const float* __restrict__ cs,
                                             float* __restrict__ corr) {
    __shared__ float row[576];
    __shared__ float hbuf[128];
    const int n = blockIdx.x;            // b*64 + d
    const int tid = threadIdx.x;
    for (int i = tid; i < 576; i += 128) row[i] = cft[(size_t)n * 576 + i];
    __syncthreads();
    float acc = b1[tid];
    for (int k = 0; k < 576; ++k) acc += row[k] * w1[k * 128 + tid];
    hbuf[tid] = 0.5f * acc * (1.0f + erff(acc * 0.70710678118654752f));
    __syncthreads();
    if (tid < 32) {
        float a2 = b2[tid];
        for (int k = 0; k < 128; ++k) a2 += hbuf[k] * w2[k * 32 + tid];
        const int b = n >> 6, d = n & 63;
        corr[(b * 32 + tid) * 64 + d] = a2 * cs[0];
    }
}

// ---------------------------------------------------------------------------
// Kernel 7: fused inverse DFT along W (24->64) and D (12->64, c2r with c_kz),
// + correction add. grid = B*O*H = 8192, 256 threads.
// ---------------------------------------------------------------------------
__global__ __launch_bounds__(256) void k_inv_yz(const float2* __restrict__ Y1,
                                                const float* __restrict__ corr,
                                                float* __restrict__ out) {
    __shared__ float2 y1[288];           // [a][kz]
    __shared__ float2 y2[64 * 12];       // [w][kz]
    __shared__ float2 tw[64];
    __shared__ float corrl[64];
    const int tid = threadIdx.x;
    const int blk = blockIdx.x;          // (b*32+o)*64 + h
    const int bo = blk >> 6;
    fill_tw(tw, tid, 256);
    for (int i = tid; i < 288; i += 256) y1[i] = Y1[(size_t)blk * 288 + i];
    if (tid < 64) corrl[tid] = corr[bo * 64 + tid];
    __syncthreads();
    // stage A: W inverse, e^{+i 2pi ky w / 64}; thread = (w, kz-triplet)
    {
        const int w = tid >> 2, kz0 = (tid & 3) * 3;
        float2 a0 = make_float2(0.f, 0.f), a1 = a0, a2 = a0;
        for (int a = 0; a < 24; ++a) {
            int kyv = a < 12 ? a : a + 40;
            float2 t = tw[(kyv * w) & 63];
            float2 f0 = y1[a * 12 + kz0];
            float2 f1 = y1[a * 12 + kz0 + 1];
            float2 f2 = y1[a * 12 + kz0 + 2];
            a0.x += f0.x * t.x - f0.y * t.y; a0.y += f0.x * t.y + f0.y * t.x;
            a1.x += f1.x * t.x - f1.y * t.y; a1.y += f1.x * t.y + f1.y * t.x;
            a2.x += f2.x * t.x - f2.y * t.y; a2.y += f2.x * t.y + f2.y * t.x;
        }
        y2[w * 12 + kz0]     = a0;
        y2[w * 12 + kz0 + 1] = a1;
        y2[w * 12 + kz0 + 2] = a2;
    }
    // per-thread fixed d: hoist the 12 D-twiddles (scaled) into registers
    float ctw[12], stw[12];
    const int d = tid & 63;
    #pragma unroll
    for (int kz = 0; kz < 12; ++kz) {
        float2 t = tw[(kz * d) & 63];
        float sc = (kz == 0 ? 1.0f : 2.0f) * (1.0f / 262144.0f);
        ctw[kz] = t.x * sc;
        stw[kz] = t.y * sc;
    }
    __syncthreads();
    const float cv = corrl[d];
    float* orow = out + (size_t)blk * 4096;
    const int wq = tid >> 6;
    for (int r = 0; r < 16; ++r) {
        int w = r * 4 + wq;
        float s = cv;
        #pragma unroll
        for (int kz = 0; kz < 12; ++kz) {
            float2 yv = y2[w * 12 + kz];
            s += yv.x * ctw[kz] - yv.y * stw[kz];  // Re(y * (c + i s)) scaled
        }
        orow[w * 64 + d] = s;
    }
}

// ---------------------------------------------------------------------------
extern "C" void kernel_launch(void* const* d_in, const int* in_sizes, int n_in,
                              void* d_out, int out_size, void* d_ws, size_t ws_size,
                              hipStream_t stream) {
    const float* x    = (const float*)d_in[0];
    const float* w1re = (const float*)d_in[1];
    const float* w1im = (const float*)d_in[2];
    const float* w2re = (const float*)d_in[3];
    const float* w2im = (const float*)d_in[4];
    const float* w3re = (const float*)d_in[5];
    const float* w3im = (const float*)d_in[6];
    const float* w4re = (const float*)d_in[7];
    const float* w4im = (const float*)d_in[8];
    const float* mw1  = (const float*)d_in[9];
    const float* mb1  = (const float*)d_in[10];
    const float* mw2  = (const float*)d_in[11];
    const float* mb2  = (const float*)d_in[12];
    const float* cs   = (const float*)d_in[13];
    float* out = (float*)d_out;

    char* ws = (char*)d_ws;
    float2* X2   = (float2*)(ws);                 // 18,874,368 B  (reused as Y1)
    float2* X3   = (float2*)(ws + 18874368);      //  7,077,888 B
    float2* F    = (float2*)(ws + 25952256);      //  7,077,888 B
    float*  cft  = (float*) (ws + 33030144);      //    589,824 B
    float*  corr = (float*) (ws + 33619968);      //     32,768 B
    float2* Y1   = X2;                            // X2 dead after k_fwd_x

    hipLaunchKernelGGL(k_fwd_zy, dim3(8192), dim3(256), 0, stream, x, X2);
    hipLaunchKernelGGL(k_fwd_x,  dim3(3072), dim3(256), 0, stream, X2, X3);
    hipLaunchKernelGGL(k_mix,    dim3(576),  dim3(384), 0, stream, X3, F,
                       w1re, w1im, w2re, w2im, w3re, w3im, w4re, w4im);
    hipLaunchKernelGGL(k_inv_x,  dim3(3072), dim3(256), 0, stream, F, Y1);
    hipLaunchKernelGGL(k_cft,    dim3(128),  dim3(256), 0, stream, x, cft);
    hipLaunchKernelGGL(k_mlp,    dim3(256),  dim3(128), 0, stream,
                       cft, mw1, mb1, mw2, mb2, cs, corr);
    hipLaunchKernelGGL(k_inv_yz, dim3(8192), dim3(256), 0, stream, Y1, corr, out);
}